// Round 14
// baseline (494.372 us; speedup 1.0000x reference)
//
#include <hip/hip_runtime.h>
#include <math.h>

#define NB 32
#define NQ 16
#define NP 196
#define OUTW 3840
#define HM_STRIDE (NQ * NP + NQ)   // 3152, members 0..2
#define HM3_STRIDE (NQ * 49 + NQ)  // 800, member 3

// ---------- resize weights (jax.image.resize, triangle kernel, antialias=True) ----------
template<int N>
__device__ __forceinline__ int calc_w(int i, float* w, int& lo) {
  constexpr float inv = (float)N / 14.0f;          // 4, 2, 0.5 — exact
  constexpr float ks  = (inv > 1.0f) ? inv : 1.0f; // kernel_scale = max(inv_scale, 1)
  constexpr float rks = 1.0f / ks;
  float sf = ((float)i + 0.5f) * inv - 0.5f;
  int l = (int)ceilf(sf - ks);
  int h = (int)floorf(sf + ks);
  if (l < 0) l = 0;
  if (h > N - 1) h = N - 1;
  int n = h - l + 1;
  float sum = 0.f;
  for (int k = 0; k < n; ++k) {
    float t = 1.0f - fabsf((float)(l + k) - sf) * rks;
    t = t > 0.f ? t : 0.f;
    w[k] = t; sum += t;
  }
  float r = 1.0f / sum;
  for (int k = 0; k < n; ++k) w[k] *= r;
  for (int k = n; k < 8; ++k) w[k] = 0.f;
  lo = l;
  return n;
}

// ---------- per-branch LDS overlays (manually unioned through one smem buffer) ----------
struct SM0 {                       // member 0: 15.9 KB
  float tmp[8 * 30 * 15];
  float wxs[14 * 8];
  float wya[14 * 8];
  int lya[14], nya[14];
  float wl[NQ * 8];
};
struct SM1 {                       // member 1: 16.2 KB
  float tmp[16 * 15 * 15];
  float wxs[14 * 4];
  float wya[14 * 8];
  int lya[14], nya[14];
  float wl[NQ * 16];
};
struct SM3 {                       // member 3: 17.3 KB
  float xl[64 * 49 + 16];
  float wl[NQ * 64];
  float w7a[14 * 8];
  int l7a[14], n7a[14];
};

// ---------- member 0 body (56->14), wave-shuffle horizontal, pixel-split ----------
__device__ __forceinline__ void rs0_body(const float* __restrict__ x,
    const float* __restrict__ W, float* __restrict__ xr,
    float* __restrict__ part, int b, SM0& sh) {
  constexpr int N = 56, CH_BLK = 8, cm = 256, NR = 30;
  const int t = threadIdx.x;
  const int s = b >> 6, chunk = (b >> 1) & 31, half = b & 1;
  const int oy0 = half * 7;
  const int r0 = half ? 26 : 0;
  const int c0 = chunk * CH_BLK;

  if (t < 14) {
    float w[8]; int lo; int n = calc_w<N>(t, w, lo);
    int off = lo - (4 * t - 2);
    for (int k = 0; k < 8; ++k) sh.wxs[t * 8 + k] = 0.f;
    for (int k = 0; k < n; ++k) sh.wxs[t * 8 + off + k] = w[k];
  } else if (t >= 64 && t < 78) {
    int i = t - 64; sh.nya[i] = calc_w<N>(i, &sh.wya[i * 8], sh.lya[i]);
  }
  for (int i = t; i < NQ * CH_BLK; i += 256) {
    int q = i / CH_BLK, cc = i - q * CH_BLK;
    sh.wl[i] = W[q * cm + c0 + cc];
  }
  __syncthreads();

  // P1: unroll 4 -> 4 loads in flight per wave (VGPR budget: 32 measured + ~24 = ~56 < 64)
  {
    const int wv = t >> 6, lane = t & 63;
    const int rr = lane / 14, j = lane - rr * 14;
    const bool act = lane < 56;
#pragma unroll 4
    for (int g = wv; g < 60; g += 4) {
      const int R = g * 4 + rr;
      const int pl = R / NR, r = r0 + (R - pl * NR);
      float4 v = make_float4(0.f, 0.f, 0.f, 0.f);
      if (act) v = *(const float4*)(x + (((size_t)(s * cm + c0 + pl)) * N + r) * N + 4 * j);
      float vmz = __shfl(v.z, lane - 1);
      float vmw = __shfl(v.w, lane - 1);
      float vpx = __shfl(v.x, lane + 1);
      float vpy = __shfl(v.y, lane + 1);
      const float* wx = &sh.wxs[j * 8];
      float acc = wx[0] * vmz + wx[1] * vmw + wx[2] * v.x + wx[3] * v.y
                + wx[4] * v.z + wx[5] * v.w + wx[6] * vpx + wx[7] * vpy;
      if (act) sh.tmp[R * 15 + j] = acc;
    }
  }
  __syncthreads();

  if (t < 98) {
    const int dy = t / 14, ox = t - dy * 14;
    const int oy = oy0 + dy;
    const int p = oy * 14 + ox;
    const int ny = sh.nya[oy], lyr = sh.lya[oy] - r0;
    const float* wy = &sh.wya[oy * 8];
    float s1 = 0.f, s2 = 0.f, y[NQ];
#pragma unroll
    for (int q = 0; q < NQ; ++q) y[q] = 0.f;
#pragma unroll 4
    for (int pl = 0; pl < CH_BLK; ++pl) {
      const float* tc = &sh.tmp[(pl * NR + lyr) * 15 + ox];
      float acc = 0.f;
      for (int k = 0; k < ny; ++k) acc = fmaf(wy[k], tc[k * 15], acc);
      xr[((size_t)s * cm + c0 + pl) * NP + p] = acc;
      s1 += acc; s2 = fmaf(acc, acc, s2);
#pragma unroll
      for (int q = 0; q < NQ; ++q) y[q] = fmaf(sh.wl[q * CH_BLK + pl], acc, y[q]);
    }
    float* pb = part + (size_t)(s * 32 + chunk) * 18 * NP + p;
    pb[0] = s1;
    pb[NP] = s2;
#pragma unroll
    for (int q = 0; q < NQ; ++q) pb[(size_t)(2 + q) * NP] = y[q];
  }
}

// ---------- member 1 body (28->14), wave-shuffle horizontal, pixel-split ----------
__device__ __forceinline__ void rs1_body(const float* __restrict__ x,
    const float* __restrict__ W, float* __restrict__ xr,
    float* __restrict__ part, int b, SM1& sh) {
  constexpr int N = 28, CH_BLK = 16, cm = 512, NR = 15;
  const int t = threadIdx.x;
  const int s = b >> 6, chunk = (b >> 1) & 31, half = b & 1;
  const int oy0 = half * 7;
  const int r0 = half ? 13 : 0;
  const int c0 = chunk * CH_BLK;

  if (t < 14) {
    float w[8]; int lo; int n = calc_w<N>(t, w, lo);
    int off = lo - (2 * t - 1);
    for (int k = 0; k < 4; ++k) sh.wxs[t * 4 + k] = 0.f;
    for (int k = 0; k < n; ++k) sh.wxs[t * 4 + off + k] = w[k];
  } else if (t >= 64 && t < 78) {
    int i = t - 64; sh.nya[i] = calc_w<N>(i, &sh.wya[i * 8], sh.lya[i]);
  }
  for (int i = t; i < NQ * CH_BLK; i += 256) {
    int q = i / CH_BLK, cc = i - q * CH_BLK;
    sh.wl[i] = W[q * cm + c0 + cc];
  }
  __syncthreads();

  // P1: unroll 4 -> 4 loads in flight
  {
    const int wv = t >> 6, lane = t & 63;
    const int rr = lane / 7, j = lane - rr * 7;
    const bool act = lane < 56;
#pragma unroll 4
    for (int g = wv; g < 30; g += 4) {
      const int R = g * 8 + rr;
      const int pl = R / NR, r = r0 + (R - pl * NR);
      float4 v = make_float4(0.f, 0.f, 0.f, 0.f);
      if (act) v = *(const float4*)(x + (((size_t)(s * cm + c0 + pl)) * N + r) * N + 4 * j);
      float vmw = __shfl(v.w, lane - 1);
      float vpx = __shfl(v.x, lane + 1);
      const int ox0 = 2 * j;
      const float* w0 = &sh.wxs[ox0 * 4];
      const float* w1 = &sh.wxs[(ox0 + 1) * 4];
      float acc0 = w0[0] * vmw + w0[1] * v.x + w0[2] * v.y + w0[3] * v.z;
      float acc1 = w1[0] * v.y + w1[1] * v.z + w1[2] * v.w + w1[3] * vpx;
      if (act) {
        sh.tmp[R * 15 + ox0] = acc0;
        sh.tmp[R * 15 + ox0 + 1] = acc1;
      }
    }
  }
  __syncthreads();

  if (t < 98) {
    const int dy = t / 14, ox = t - dy * 14;
    const int oy = oy0 + dy;
    const int p = oy * 14 + ox;
    const int ny = sh.nya[oy], lyr = sh.lya[oy] - r0;
    const float* wy = &sh.wya[oy * 8];
    float s1 = 0.f, s2 = 0.f, y[NQ];
#pragma unroll
    for (int q = 0; q < NQ; ++q) y[q] = 0.f;
#pragma unroll 4
    for (int pl = 0; pl < CH_BLK; ++pl) {
      const float* tc = &sh.tmp[(pl * NR + lyr) * 15 + ox];
      float acc = 0.f;
      for (int k = 0; k < ny; ++k) acc = fmaf(wy[k], tc[k * 15], acc);
      xr[((size_t)s * cm + c0 + pl) * NP + p] = acc;
      s1 += acc; s2 = fmaf(acc, acc, s2);
#pragma unroll
      for (int q = 0; q < NQ; ++q) y[q] = fmaf(sh.wl[q * CH_BLK + pl], acc, y[q]);
    }
    float* pb = part + (size_t)(s * 32 + chunk) * 18 * NP + p;
    pb[0] = s1;
    pb[NP] = s2;
#pragma unroll
    for (int q = 0; q < NQ; ++q) pb[(size_t)(2 + q) * NP] = y[q];
  }
}

// ---------- member 2 body (identity resize), register-direct, 4 loads in flight ----------
__device__ __forceinline__ void rs2_body(const float* __restrict__ x,
    const float* __restrict__ W, float* __restrict__ part, int b) {
  const int t = threadIdx.x;
  if (t >= NP) return;
  const int s = b >> 5, chunk = b & 31;
  const int c0 = chunk * 32;
  const float* src = x + ((size_t)s * 1024 + c0) * NP + t;
  float s1 = 0.f, s2 = 0.f, y[NQ];
#pragma unroll
  for (int q = 0; q < NQ; ++q) y[q] = 0.f;
  for (int c = 0; c < 32; c += 4) {
    float v0 = src[(size_t)(c + 0) * NP];
    float v1 = src[(size_t)(c + 1) * NP];
    float v2 = src[(size_t)(c + 2) * NP];
    float v3 = src[(size_t)(c + 3) * NP];
    s1 += v0 + v1 + v2 + v3;
    s2 = fmaf(v0, v0, s2); s2 = fmaf(v1, v1, s2);
    s2 = fmaf(v2, v2, s2); s2 = fmaf(v3, v3, s2);
#pragma unroll
    for (int q = 0; q < NQ; ++q) {
      float acc = y[q];
      acc = fmaf(W[q * 1024 + c0 + c + 0], v0, acc);
      acc = fmaf(W[q * 1024 + c0 + c + 1], v1, acc);
      acc = fmaf(W[q * 1024 + c0 + c + 2], v2, acc);
      acc = fmaf(W[q * 1024 + c0 + c + 3], v3, acc);
      y[q] = acc;
    }
  }
  float* pb = part + (size_t)(s * 32 + chunk) * 18 * NP + t;
  pb[0] = s1;
  pb[NP] = s2;
#pragma unroll
  for (int q = 0; q < NQ; ++q) pb[(size_t)(2 + q) * NP] = y[q];
}

// ---------- member 3 body (7->14 upsample, <=2x2 taps, no xr) ----------
__device__ __forceinline__ void rs3_body(const float* __restrict__ x,
    const float* __restrict__ W, float* __restrict__ part, int b, SM3& sh) {
  const int t = threadIdx.x;
  const int s = b >> 5, chunk = b & 31;
  const int c0 = chunk * 64;

  if (t < 14) sh.n7a[t] = calc_w<7>(t, &sh.w7a[t * 8], sh.l7a[t]);
  for (int i = t; i < NQ * 64; i += 256) {
    int q = i >> 6, cc = i & 63;
    sh.wl[i] = W[q * 2048 + c0 + cc];
  }
  const float4* src4 = (const float4*)(x + ((size_t)s * 2048 + c0) * 49);
  float4* x4 = (float4*)sh.xl;
  for (int i = t; i < 64 * 49 / 4; i += 256) x4[i] = src4[i];
  __syncthreads();

  if (t < NP) {
    const int oy = t / 14, ox = t - oy * 14;
    const int ly = sh.l7a[oy], lx = sh.l7a[ox];
    const float wy0 = sh.w7a[oy * 8], wy1 = (sh.n7a[oy] > 1) ? sh.w7a[oy * 8 + 1] : 0.f;
    const float wx0 = sh.w7a[ox * 8], wx1 = (sh.n7a[ox] > 1) ? sh.w7a[ox * 8 + 1] : 0.f;
    const int base0 = ly * 7 + lx;
    float s1 = 0.f, s2 = 0.f, y[NQ];
#pragma unroll
    for (int q = 0; q < NQ; ++q) y[q] = 0.f;
#pragma unroll 4
    for (int c = 0; c < 64; ++c) {
      const float* bb = &sh.xl[c * 49 + base0];
      float v = wy0 * fmaf(wx1, bb[1], wx0 * bb[0]) + wy1 * fmaf(wx1, bb[8], wx0 * bb[7]);
      s1 += v; s2 = fmaf(v, v, s2);
#pragma unroll
      for (int q = 0; q < NQ; ++q) y[q] = fmaf(sh.wl[q * 64 + c], v, y[q]);
    }
    float* pb = part + (size_t)(s * 32 + chunk) * 18 * NP + t;
    pb[0] = s1;
    pb[NP] = s2;
#pragma unroll
    for (int q = 0; q < NQ; ++q) pb[(size_t)(2 + q) * NP] = y[q];
  }
}

// ---------- K1: ALL members in one launch (6144 blocks, no grid drains) ----------
// grid: m0 [0,2048) m1 [2048,4096) m2 [4096,5120) m3 [5120,6144)
struct RSArgs {
  const float* x[4];
  const float* W[4];
  float* xr[2];
  float* part[4];
};

__global__ __launch_bounds__(256, 8) void k_rs_all(RSArgs A) {
  __shared__ __align__(16) char smem[17280];   // union of SM0/SM1/SM3 (max 17.3 KB)
  int b = blockIdx.x;
  if (b < 2048) {
    rs0_body(A.x[0], A.W[0], A.xr[0], A.part[0], b, *(SM0*)smem);
  } else if (b < 4096) {
    rs1_body(A.x[1], A.W[1], A.xr[1], A.part[1], b - 2048, *(SM1*)smem);
  } else if (b < 5120) {
    rs2_body(A.x[2], A.W[2], A.part[2], b - 4096);
  } else {
    rs3_body(A.x[3], A.W[3], A.part[3], b - 5120, *(SM3*)smem);
  }
}

// ---------- K2: combine partials, H, G^-1, HM = rsd*(H^T M), e; m3: adjoint HM ----------
struct HeadArgs {
  const float* part[4];
  const float* W[4];
  float* hm[4];
  int cm[4];
};

__global__ __launch_bounds__(256) void k_head(HeadArgs A) {
  const int m = blockIdx.y, s = blockIdx.x, t = threadIdx.x;
  const int cm = A.cm[m];
  const float* W = A.W[m];
  const float* part = A.part[m];
  float* hm = A.hm[m];

  __shared__ float red[256];
  __shared__ float wsum[NQ];
  __shared__ float Hl[NQ * NP];
  __shared__ float HMl[NQ * NP];
  __shared__ float mul[NP], rsdl[NP];
  __shared__ float aug[16 * 33];
  __shared__ float Ml[256];
  __shared__ float el[NQ];
  __shared__ float w7[14 * 8];
  __shared__ int l7[14], n7[14];
  __shared__ float Radj[14 * 7];
  __shared__ float t2[NQ * 7 * 14];

  { int q = t >> 4, l = t & 15;
    float p = 0.f;
    for (int c = l; c < cm; c += 16) p += W[q * cm + c];
    red[t] = p; }
  __syncthreads();
  if (t < NQ) { float v = 0.f; for (int k = 0; k < 16; ++k) v += red[t * 16 + k]; wsum[t] = v; }
  __syncthreads();

  if (t < NP) {
    float s1 = 0.f, s2 = 0.f, y[NQ];
#pragma unroll
    for (int q = 0; q < NQ; ++q) y[q] = 0.f;
    for (int ch = 0; ch < 32; ++ch) {
      const float* pb = part + (size_t)(s * 32 + ch) * 18 * NP + t;
      s1 += pb[0];
      s2 += pb[NP];
#pragma unroll
      for (int q = 0; q < NQ; ++q) y[q] += pb[(size_t)(2 + q) * NP];
    }
    float mu = s1 / (float)cm;
    float var = (s2 - s1 * mu) / (float)(cm - 1);
    float rsd = (var > 0.f) ? (1.0f / sqrtf(var)) : 0.f;
    mul[t] = mu; rsdl[t] = rsd;
#pragma unroll
    for (int q = 0; q < NQ; ++q) {
      float arg = (y[q] - wsum[q] * mu) * rsd;
      Hl[q * NP + t] = 1.0f / (1.0f + expf(-arg));
    }
  }
  __syncthreads();

  { int q1 = t >> 4, q2 = t & 15;
    float g = 0.f;
    for (int p = 0; p < NP; ++p) g = fmaf(Hl[q1 * NP + p], Hl[q2 * NP + p], g);
    aug[q1 * 33 + q2] = g;
    aug[q1 * 33 + 16 + q2] = (q1 == q2) ? 1.0f : 0.f; }
  __syncthreads();

  for (int k = 0; k < 16; ++k) {
    float rpv = 1.0f / aug[k * 33 + k];
    __syncthreads();
    if (t < 32) aug[k * 33 + t] *= rpv;
    __syncthreads();
    int i = t >> 4, j = t & 15;
    float f = aug[i * 33 + k];
    __syncthreads();
    if (i != k) {
      aug[i * 33 + j]      -= f * aug[k * 33 + j];
      aug[i * 33 + 16 + j] -= f * aug[k * 33 + 16 + j];
    }
    __syncthreads();
  }
  { int i = t >> 4, j = t & 15; Ml[t] = aug[i * 33 + 16 + j]; }
  __syncthreads();

  if (t < NP) {
    float r_ = rsdl[t];
#pragma unroll
    for (int j = 0; j < NQ; ++j) {
      float acc = 0.f;
#pragma unroll
      for (int q = 0; q < NQ; ++q) acc = fmaf(Ml[j * 16 + q], Hl[q * NP + t], acc);
      HMl[j * NP + t] = acc * r_;
    }
  }
  __syncthreads();

  { int j = t >> 4, l = t & 15;
    float p = 0.f;
    for (int pp = l; pp < NP; pp += 16) p = fmaf(mul[pp], HMl[j * NP + pp], p);
    red[t] = p; }
  __syncthreads();
  if (t < NQ) { float v = 0.f; for (int k = 0; k < 16; ++k) v += red[t * 16 + k]; el[t] = v; }
  __syncthreads();

  if (m < 3) {
    float* dst = hm + (size_t)s * HM_STRIDE;
    for (int i = t; i < NQ * NP; i += 256) dst[i] = HMl[i];
    if (t < NQ) dst[NQ * NP + t] = el[t];
  } else {
    if (t < 14) n7[t] = calc_w<7>(t, &w7[t * 8], l7[t]);
    __syncthreads();
    if (t < 98) {
      int oy = t / 7, iy = t - oy * 7;
      int k = iy - l7[oy];
      Radj[oy * 7 + iy] = (k >= 0 && k < n7[oy]) ? w7[oy * 8 + k] : 0.f;
    }
    __syncthreads();
    for (int i = t; i < NQ * 7 * 14; i += 256) {   // t2[j][iy][ox]
      int j = i / 98, rem = i - j * 98, iy = rem / 14, ox = rem - iy * 14;
      float acc = 0.f;
#pragma unroll
      for (int oy = 0; oy < 14; ++oy) acc = fmaf(Radj[oy * 7 + iy], HMl[j * NP + oy * 14 + ox], acc);
      t2[i] = acc;
    }
    __syncthreads();
    float* dst = hm + (size_t)s * HM3_STRIDE;
    for (int i = t; i < NQ * 49; i += 256) {       // dst[j][iy][ix]
      int j = i / 49, rem = i - j * 49, iy = rem / 7, ix = rem - iy * 7;
      float acc = 0.f;
#pragma unroll
      for (int ox = 0; ox < 14; ++ox) acc = fmaf(Radj[ox * 7 + ix], t2[j * 98 + iy * 14 + ox], acc);
      dst[i] = acc;
    }
    if (t < NQ) dst[NQ * 49 + t] = el[t];
  }
}

// ---------- K3: b[cc][j] = dot(row, HM[j]) - e[j]; out = var_j(b) ----------
#define CC3 32
struct VarArgs {
  const float* src[4];
  const float* hm[4];
  int cm[4];
  int ooff[4];
};

// grid: m0 [0,256) m1 [256,768) m2 [768,1792) m3 [1792,3840)
__global__ __launch_bounds__(512) void k_var(VarArgs A, float* __restrict__ out) {
  __shared__ __align__(16) float tile[CC3 * NP];
  __shared__ __align__(16) float hml[NQ * NP];
  __shared__ float el[NQ];
  int b = blockIdx.x;
  int m;
  if (b < 256)       { m = 0; }
  else if (b < 768)  { m = 1; b -= 256; }
  else if (b < 1792) { m = 2; b -= 768; }
  else               { m = 3; b -= 1792; }
  const int t = threadIdx.x;
  const int cc = t >> 4, j = t & 15;

  if (m < 3) {
    const int cm = A.cm[m];
    const int nch = cm / CC3;
    const int s = b / nch;
    const int ch = b % nch;
    const float4* src = (const float4*)(A.src[m] + ((size_t)s * cm + ch * CC3) * NP);
    float4* t4 = (float4*)tile;
    for (int i = t; i < CC3 * NP / 4; i += 512) t4[i] = src[i];
    const float4* hsrc = (const float4*)(A.hm[m] + (size_t)s * HM_STRIDE);
    float4* h4 = (float4*)hml;
    for (int i = t; i < NQ * NP / 4; i += 512) h4[i] = hsrc[i];
    if (t < NQ) el[t] = A.hm[m][(size_t)s * HM_STRIDE + NQ * NP + t];
    __syncthreads();

    const float4* tr = (const float4*)(tile + cc * NP);
    const float4* hr = (const float4*)(hml + j * NP);
    float acc = 0.f;
#pragma unroll 7
    for (int p4 = 0; p4 < NP / 4; ++p4) {
      float4 a = tr[p4], b2 = hr[p4];
      acc = fmaf(a.x, b2.x, acc);
      acc = fmaf(a.y, b2.y, acc);
      acc = fmaf(a.z, b2.z, acc);
      acc = fmaf(a.w, b2.w, acc);
    }
    float bv = acc - el[j];
    float s1 = bv;
    s1 += __shfl_xor(s1, 1, 16); s1 += __shfl_xor(s1, 2, 16);
    s1 += __shfl_xor(s1, 4, 16); s1 += __shfl_xor(s1, 8, 16);
    float mean = s1 * (1.0f / 16.0f);
    float d = bv - mean;
    float s2 = d * d;
    s2 += __shfl_xor(s2, 1, 16); s2 += __shfl_xor(s2, 2, 16);
    s2 += __shfl_xor(s2, 4, 16); s2 += __shfl_xor(s2, 8, 16);
    if (j == 0) out[(size_t)s * OUTW + A.ooff[m] + ch * CC3 + cc] = s2 * (1.0f / 15.0f);
  } else {
    const int s = b / 64;
    const int ch = b % 64;
    const float4* src = (const float4*)(A.src[3] + ((size_t)s * 2048 + ch * CC3) * 49);
    float4* t4 = (float4*)tile;
    for (int i = t; i < CC3 * 49 / 4; i += 512) t4[i] = src[i];
    const float4* hsrc = (const float4*)(A.hm[3] + (size_t)s * HM3_STRIDE);
    float4* h4 = (float4*)hml;
    for (int i = t; i < NQ * 49 / 4; i += 512) h4[i] = hsrc[i];
    if (t < NQ) el[t] = A.hm[3][(size_t)s * HM3_STRIDE + NQ * 49 + t];
    __syncthreads();

    const float* tr = tile + cc * 49;
    const float* hr = hml + j * 49;
    float acc = 0.f;
#pragma unroll
    for (int i = 0; i < 49; ++i) acc = fmaf(tr[i], hr[i], acc);
    float bv = acc - el[j];
    float s1 = bv;
    s1 += __shfl_xor(s1, 1, 16); s1 += __shfl_xor(s1, 2, 16);
    s1 += __shfl_xor(s1, 4, 16); s1 += __shfl_xor(s1, 8, 16);
    float mean = s1 * (1.0f / 16.0f);
    float d = bv - mean;
    float s2 = d * d;
    s2 += __shfl_xor(s2, 1, 16); s2 += __shfl_xor(s2, 2, 16);
    s2 += __shfl_xor(s2, 4, 16); s2 += __shfl_xor(s2, 8, 16);
    if (j == 0) out[(size_t)s * OUTW + 1792 + ch * CC3 + cc] = s2 * (1.0f / 15.0f);
  }
}

extern "C" void kernel_launch(void* const* d_in, const int* in_sizes, int n_in,
                              void* d_out, int out_size, void* d_ws, size_t ws_size,
                              hipStream_t stream) {
  const float* x0 = (const float*)d_in[0];
  const float* W0 = (const float*)d_in[1];
  const float* x1 = (const float*)d_in[2];
  const float* W1 = (const float*)d_in[3];
  const float* x2 = (const float*)d_in[4];
  const float* W2 = (const float*)d_in[5];
  const float* x3 = (const float*)d_in[6];
  const float* W3 = (const float*)d_in[7];
  float* out = (float*)d_out;
  float* ws = (float*)d_ws;

  // workspace layout (floats)
  float* xr0 = ws;                                   // 32*256*196
  float* xr1 = xr0 + (size_t)NB * 256 * NP;          // 32*512*196
  float* part0 = xr1 + (size_t)NB * 512 * NP;
  size_t plm = (size_t)NB * 32 * 18 * NP;            // per member
  float* part1 = part0 + plm;
  float* part2 = part1 + plm;
  float* part3 = part2 + plm;
  float* hm0 = part3 + plm;
  float* hm1 = hm0 + (size_t)NB * HM_STRIDE;
  float* hm2 = hm1 + (size_t)NB * HM_STRIDE;
  float* hm3 = hm2 + (size_t)NB * HM_STRIDE;         // 32*800

  // K1: single launch, all members (m0 blocks first — longest work first)
  RSArgs R;
  R.x[0] = x0; R.x[1] = x1; R.x[2] = x2; R.x[3] = x3;
  R.W[0] = W0; R.W[1] = W1; R.W[2] = W2; R.W[3] = W3;
  R.xr[0] = xr0; R.xr[1] = xr1;
  R.part[0] = part0; R.part[1] = part1; R.part[2] = part2; R.part[3] = part3;
  k_rs_all<<<6144, 256, 0, stream>>>(R);

  // K2: head
  HeadArgs A;
  A.part[0] = part0; A.part[1] = part1; A.part[2] = part2; A.part[3] = part3;
  A.W[0] = W0; A.W[1] = W1; A.W[2] = W2; A.W[3] = W3;
  A.hm[0] = hm0; A.hm[1] = hm1; A.hm[2] = hm2; A.hm[3] = hm3;
  A.cm[0] = 256; A.cm[1] = 512; A.cm[2] = 1024; A.cm[3] = 2048;
  k_head<<<dim3(NB, 4), 256, 0, stream>>>(A);

  // K3: var
  VarArgs V;
  V.src[0] = xr0; V.src[1] = xr1; V.src[2] = x2; V.src[3] = x3;
  V.hm[0] = hm0; V.hm[1] = hm1; V.hm[2] = hm2; V.hm[3] = hm3;
  V.cm[0] = 256; V.cm[1] = 512; V.cm[2] = 1024; V.cm[3] = 2048;
  V.ooff[0] = 0; V.ooff[1] = 256; V.ooff[2] = 768; V.ooff[3] = 1792;
  k_var<<<3840, 512, 0, stream>>>(V, out);
  (void)in_sizes; (void)n_in; (void)out_size; (void)ws_size;
}

// Round 15
// 166.430 us; speedup vs baseline: 2.9705x; 2.9705x over previous
//
#include <hip/hip_runtime.h>
#include <math.h>

#define NB 32
#define NQ 16
#define NP 196
#define OUTW 3840
#define HM_STRIDE (NQ * NP + NQ)   // 3152, members 0..2
#define HM3_STRIDE (NQ * 49 + NQ)  // 800, member 3

// ---------- resize weights (jax.image.resize, triangle kernel, antialias=True) ----------
template<int N>
__device__ __forceinline__ int calc_w(int i, float* w, int& lo) {
  constexpr float inv = (float)N / 14.0f;          // 4, 2, 0.5 — exact
  constexpr float ks  = (inv > 1.0f) ? inv : 1.0f; // kernel_scale = max(inv_scale, 1)
  constexpr float rks = 1.0f / ks;
  float sf = ((float)i + 0.5f) * inv - 0.5f;
  int l = (int)ceilf(sf - ks);
  int h = (int)floorf(sf + ks);
  if (l < 0) l = 0;
  if (h > N - 1) h = N - 1;
  int n = h - l + 1;
  float sum = 0.f;
  for (int k = 0; k < n; ++k) {
    float t = 1.0f - fabsf((float)(l + k) - sf) * rks;
    t = t > 0.f ? t : 0.f;
    w[k] = t; sum += t;
  }
  float r = 1.0f / sum;
  for (int k = 0; k < n; ++k) w[k] *= r;
  for (int k = n; k < 8; ++k) w[k] = 0.f;
  lo = l;
  return n;
}

// ---------- per-branch LDS overlays (manually unioned through one smem buffer) ----------
struct SM0 {                       // member 0: 15.9 KB
  float tmp[8 * 30 * 15];
  float wxs[14 * 8];
  float wya[14 * 8];
  int lya[14], nya[14];
  float wl[NQ * 8];
};
struct SM1 {                       // member 1: 16.2 KB
  float tmp[16 * 15 * 15];
  float wxs[14 * 4];
  float wya[14 * 8];
  int lya[14], nya[14];
  float wl[NQ * 16];
};
struct SM3 {                       // member 3: 17.3 KB
  float xl[64 * 49 + 16];
  float wl[NQ * 64];
  float w7a[14 * 8];
  int l7a[14], n7a[14];
};

// ---------- member 0 body (56->14), wave-shuffle horizontal, pixel-split ----------
__device__ __forceinline__ void rs0_body(const float* __restrict__ x,
    const float* __restrict__ W, float* __restrict__ xr,
    float* __restrict__ part, int b, SM0& sh) {
  constexpr int N = 56, CH_BLK = 8, cm = 256, NR = 30;
  const int t = threadIdx.x;
  const int s = b >> 6, chunk = (b >> 1) & 31, half = b & 1;
  const int oy0 = half * 7;
  const int r0 = half ? 26 : 0;
  const int c0 = chunk * CH_BLK;

  if (t < 14) {
    float w[8]; int lo; int n = calc_w<N>(t, w, lo);
    int off = lo - (4 * t - 2);
    for (int k = 0; k < 8; ++k) sh.wxs[t * 8 + k] = 0.f;
    for (int k = 0; k < n; ++k) sh.wxs[t * 8 + off + k] = w[k];
  } else if (t >= 64 && t < 78) {
    int i = t - 64; sh.nya[i] = calc_w<N>(i, &sh.wya[i * 8], sh.lya[i]);
  }
  for (int i = t; i < NQ * CH_BLK; i += 256) {
    int q = i / CH_BLK, cc = i - q * CH_BLK;
    sh.wl[i] = W[q * cm + c0 + cc];
  }
  __syncthreads();

  // P1: unroll 4 — ONLY change vs r12 (load-staging loop, no accumulator pressure)
  {
    const int wv = t >> 6, lane = t & 63;
    const int rr = lane / 14, j = lane - rr * 14;
    const bool act = lane < 56;
#pragma unroll 4
    for (int g = wv; g < 60; g += 4) {
      const int R = g * 4 + rr;
      const int pl = R / NR, r = r0 + (R - pl * NR);
      float4 v = make_float4(0.f, 0.f, 0.f, 0.f);
      if (act) v = *(const float4*)(x + (((size_t)(s * cm + c0 + pl)) * N + r) * N + 4 * j);
      float vmz = __shfl(v.z, lane - 1);
      float vmw = __shfl(v.w, lane - 1);
      float vpx = __shfl(v.x, lane + 1);
      float vpy = __shfl(v.y, lane + 1);
      const float* wx = &sh.wxs[j * 8];
      float acc = wx[0] * vmz + wx[1] * vmw + wx[2] * v.x + wx[3] * v.y
                + wx[4] * v.z + wx[5] * v.w + wx[6] * vpx + wx[7] * vpy;
      if (act) sh.tmp[R * 15 + j] = acc;
    }
  }
  __syncthreads();

  if (t < 98) {
    const int dy = t / 14, ox = t - dy * 14;
    const int oy = oy0 + dy;
    const int p = oy * 14 + ox;
    const int ny = sh.nya[oy], lyr = sh.lya[oy] - r0;
    const float* wy = &sh.wya[oy * 8];
    float s1 = 0.f, s2 = 0.f, y[NQ];
#pragma unroll
    for (int q = 0; q < NQ; ++q) y[q] = 0.f;
#pragma unroll 2
    for (int pl = 0; pl < CH_BLK; ++pl) {
      const float* tc = &sh.tmp[(pl * NR + lyr) * 15 + ox];
      float acc = 0.f;
      for (int k = 0; k < ny; ++k) acc = fmaf(wy[k], tc[k * 15], acc);
      xr[((size_t)s * cm + c0 + pl) * NP + p] = acc;
      s1 += acc; s2 = fmaf(acc, acc, s2);
#pragma unroll
      for (int q = 0; q < NQ; ++q) y[q] = fmaf(sh.wl[q * CH_BLK + pl], acc, y[q]);
    }
    float* pb = part + (size_t)(s * 32 + chunk) * 18 * NP + p;
    pb[0] = s1;
    pb[NP] = s2;
#pragma unroll
    for (int q = 0; q < NQ; ++q) pb[(size_t)(2 + q) * NP] = y[q];
  }
}

// ---------- member 1 body (28->14), wave-shuffle horizontal, pixel-split ----------
__device__ __forceinline__ void rs1_body(const float* __restrict__ x,
    const float* __restrict__ W, float* __restrict__ xr,
    float* __restrict__ part, int b, SM1& sh) {
  constexpr int N = 28, CH_BLK = 16, cm = 512, NR = 15;
  const int t = threadIdx.x;
  const int s = b >> 6, chunk = (b >> 1) & 31, half = b & 1;
  const int oy0 = half * 7;
  const int r0 = half ? 13 : 0;
  const int c0 = chunk * CH_BLK;

  if (t < 14) {
    float w[8]; int lo; int n = calc_w<N>(t, w, lo);
    int off = lo - (2 * t - 1);
    for (int k = 0; k < 4; ++k) sh.wxs[t * 4 + k] = 0.f;
    for (int k = 0; k < n; ++k) sh.wxs[t * 4 + off + k] = w[k];
  } else if (t >= 64 && t < 78) {
    int i = t - 64; sh.nya[i] = calc_w<N>(i, &sh.wya[i * 8], sh.lya[i]);
  }
  for (int i = t; i < NQ * CH_BLK; i += 256) {
    int q = i / CH_BLK, cc = i - q * CH_BLK;
    sh.wl[i] = W[q * cm + c0 + cc];
  }
  __syncthreads();

  // P1: unroll 4 — ONLY change vs r12
  {
    const int wv = t >> 6, lane = t & 63;
    const int rr = lane / 7, j = lane - rr * 7;
    const bool act = lane < 56;
#pragma unroll 4
    for (int g = wv; g < 30; g += 4) {
      const int R = g * 8 + rr;
      const int pl = R / NR, r = r0 + (R - pl * NR);
      float4 v = make_float4(0.f, 0.f, 0.f, 0.f);
      if (act) v = *(const float4*)(x + (((size_t)(s * cm + c0 + pl)) * N + r) * N + 4 * j);
      float vmw = __shfl(v.w, lane - 1);
      float vpx = __shfl(v.x, lane + 1);
      const int ox0 = 2 * j;
      const float* w0 = &sh.wxs[ox0 * 4];
      const float* w1 = &sh.wxs[(ox0 + 1) * 4];
      float acc0 = w0[0] * vmw + w0[1] * v.x + w0[2] * v.y + w0[3] * v.z;
      float acc1 = w1[0] * v.y + w1[1] * v.z + w1[2] * v.w + w1[3] * vpx;
      if (act) {
        sh.tmp[R * 15 + ox0] = acc0;
        sh.tmp[R * 15 + ox0 + 1] = acc1;
      }
    }
  }
  __syncthreads();

  if (t < 98) {
    const int dy = t / 14, ox = t - dy * 14;
    const int oy = oy0 + dy;
    const int p = oy * 14 + ox;
    const int ny = sh.nya[oy], lyr = sh.lya[oy] - r0;
    const float* wy = &sh.wya[oy * 8];
    float s1 = 0.f, s2 = 0.f, y[NQ];
#pragma unroll
    for (int q = 0; q < NQ; ++q) y[q] = 0.f;
#pragma unroll 2
    for (int pl = 0; pl < CH_BLK; ++pl) {
      const float* tc = &sh.tmp[(pl * NR + lyr) * 15 + ox];
      float acc = 0.f;
      for (int k = 0; k < ny; ++k) acc = fmaf(wy[k], tc[k * 15], acc);
      xr[((size_t)s * cm + c0 + pl) * NP + p] = acc;
      s1 += acc; s2 = fmaf(acc, acc, s2);
#pragma unroll
      for (int q = 0; q < NQ; ++q) y[q] = fmaf(sh.wl[q * CH_BLK + pl], acc, y[q]);
    }
    float* pb = part + (size_t)(s * 32 + chunk) * 18 * NP + p;
    pb[0] = s1;
    pb[NP] = s2;
#pragma unroll
    for (int q = 0; q < NQ; ++q) pb[(size_t)(2 + q) * NP] = y[q];
  }
}

// ---------- member 2 body (identity resize), register-direct (r12-exact) ----------
__device__ __forceinline__ void rs2_body(const float* __restrict__ x,
    const float* __restrict__ W, float* __restrict__ part, int b) {
  const int t = threadIdx.x;
  if (t >= NP) return;
  const int s = b >> 5, chunk = b & 31;
  const int c0 = chunk * 32;
  const float* src = x + ((size_t)s * 1024 + c0) * NP + t;
  float s1 = 0.f, s2 = 0.f, y[NQ];
#pragma unroll
  for (int q = 0; q < NQ; ++q) y[q] = 0.f;
  for (int c = 0; c < 32; ++c) {
    float v = src[(size_t)c * NP];
    s1 += v; s2 = fmaf(v, v, s2);
#pragma unroll
    for (int q = 0; q < NQ; ++q) y[q] = fmaf(W[q * 1024 + c0 + c], v, y[q]);
  }
  float* pb = part + (size_t)(s * 32 + chunk) * 18 * NP + t;
  pb[0] = s1;
  pb[NP] = s2;
#pragma unroll
  for (int q = 0; q < NQ; ++q) pb[(size_t)(2 + q) * NP] = y[q];
}

// ---------- member 3 body (7->14 upsample, <=2x2 taps, no xr) (r12-exact) ----------
__device__ __forceinline__ void rs3_body(const float* __restrict__ x,
    const float* __restrict__ W, float* __restrict__ part, int b, SM3& sh) {
  const int t = threadIdx.x;
  const int s = b >> 5, chunk = b & 31;
  const int c0 = chunk * 64;

  if (t < 14) sh.n7a[t] = calc_w<7>(t, &sh.w7a[t * 8], sh.l7a[t]);
  for (int i = t; i < NQ * 64; i += 256) {
    int q = i >> 6, cc = i & 63;
    sh.wl[i] = W[q * 2048 + c0 + cc];
  }
  const float4* src4 = (const float4*)(x + ((size_t)s * 2048 + c0) * 49);
  float4* x4 = (float4*)sh.xl;
  for (int i = t; i < 64 * 49 / 4; i += 256) x4[i] = src4[i];
  __syncthreads();

  if (t < NP) {
    const int oy = t / 14, ox = t - oy * 14;
    const int ly = sh.l7a[oy], lx = sh.l7a[ox];
    const float wy0 = sh.w7a[oy * 8], wy1 = (sh.n7a[oy] > 1) ? sh.w7a[oy * 8 + 1] : 0.f;
    const float wx0 = sh.w7a[ox * 8], wx1 = (sh.n7a[ox] > 1) ? sh.w7a[ox * 8 + 1] : 0.f;
    const int base0 = ly * 7 + lx;
    float s1 = 0.f, s2 = 0.f, y[NQ];
#pragma unroll
    for (int q = 0; q < NQ; ++q) y[q] = 0.f;
    for (int c = 0; c < 64; ++c) {
      const float* bb = &sh.xl[c * 49 + base0];
      float v = wy0 * fmaf(wx1, bb[1], wx0 * bb[0]) + wy1 * fmaf(wx1, bb[8], wx0 * bb[7]);
      s1 += v; s2 = fmaf(v, v, s2);
#pragma unroll
      for (int q = 0; q < NQ; ++q) y[q] = fmaf(sh.wl[q * 64 + c], v, y[q]);
    }
    float* pb = part + (size_t)(s * 32 + chunk) * 18 * NP + t;
    pb[0] = s1;
    pb[NP] = s2;
#pragma unroll
    for (int q = 0; q < NQ; ++q) pb[(size_t)(2 + q) * NP] = y[q];
  }
}

// ---------- K1: ALL members in one launch (6144 blocks, no grid drains) ----------
// grid: m0 [0,2048) m1 [2048,4096) m2 [4096,5120) m3 [5120,6144)
struct RSArgs {
  const float* x[4];
  const float* W[4];
  float* xr[2];
  float* part[4];
};

__global__ __launch_bounds__(256, 8) void k_rs_all(RSArgs A) {
  __shared__ __align__(16) char smem[17280];   // union of SM0/SM1/SM3 (max 17.3 KB)
  int b = blockIdx.x;
  if (b < 2048) {
    rs0_body(A.x[0], A.W[0], A.xr[0], A.part[0], b, *(SM0*)smem);
  } else if (b < 4096) {
    rs1_body(A.x[1], A.W[1], A.xr[1], A.part[1], b - 2048, *(SM1*)smem);
  } else if (b < 5120) {
    rs2_body(A.x[2], A.W[2], A.part[2], b - 4096);
  } else {
    rs3_body(A.x[3], A.W[3], A.part[3], b - 5120, *(SM3*)smem);
  }
}

// ---------- K2: combine partials, H, G^-1, HM = rsd*(H^T M), e; m3: adjoint HM ----------
struct HeadArgs {
  const float* part[4];
  const float* W[4];
  float* hm[4];
  int cm[4];
};

__global__ __launch_bounds__(256) void k_head(HeadArgs A) {
  const int m = blockIdx.y, s = blockIdx.x, t = threadIdx.x;
  const int cm = A.cm[m];
  const float* W = A.W[m];
  const float* part = A.part[m];
  float* hm = A.hm[m];

  __shared__ float red[256];
  __shared__ float wsum[NQ];
  __shared__ float Hl[NQ * NP];
  __shared__ float HMl[NQ * NP];
  __shared__ float mul[NP], rsdl[NP];
  __shared__ float aug[16 * 33];
  __shared__ float Ml[256];
  __shared__ float el[NQ];
  __shared__ float w7[14 * 8];
  __shared__ int l7[14], n7[14];
  __shared__ float Radj[14 * 7];
  __shared__ float t2[NQ * 7 * 14];

  { int q = t >> 4, l = t & 15;
    float p = 0.f;
    for (int c = l; c < cm; c += 16) p += W[q * cm + c];
    red[t] = p; }
  __syncthreads();
  if (t < NQ) { float v = 0.f; for (int k = 0; k < 16; ++k) v += red[t * 16 + k]; wsum[t] = v; }
  __syncthreads();

  if (t < NP) {
    float s1 = 0.f, s2 = 0.f, y[NQ];
#pragma unroll
    for (int q = 0; q < NQ; ++q) y[q] = 0.f;
    for (int ch = 0; ch < 32; ++ch) {
      const float* pb = part + (size_t)(s * 32 + ch) * 18 * NP + t;
      s1 += pb[0];
      s2 += pb[NP];
#pragma unroll
      for (int q = 0; q < NQ; ++q) y[q] += pb[(size_t)(2 + q) * NP];
    }
    float mu = s1 / (float)cm;
    float var = (s2 - s1 * mu) / (float)(cm - 1);
    float rsd = (var > 0.f) ? (1.0f / sqrtf(var)) : 0.f;
    mul[t] = mu; rsdl[t] = rsd;
#pragma unroll
    for (int q = 0; q < NQ; ++q) {
      float arg = (y[q] - wsum[q] * mu) * rsd;
      Hl[q * NP + t] = 1.0f / (1.0f + expf(-arg));
    }
  }
  __syncthreads();

  { int q1 = t >> 4, q2 = t & 15;
    float g = 0.f;
    for (int p = 0; p < NP; ++p) g = fmaf(Hl[q1 * NP + p], Hl[q2 * NP + p], g);
    aug[q1 * 33 + q2] = g;
    aug[q1 * 33 + 16 + q2] = (q1 == q2) ? 1.0f : 0.f; }
  __syncthreads();

  for (int k = 0; k < 16; ++k) {
    float rpv = 1.0f / aug[k * 33 + k];
    __syncthreads();
    if (t < 32) aug[k * 33 + t] *= rpv;
    __syncthreads();
    int i = t >> 4, j = t & 15;
    float f = aug[i * 33 + k];
    __syncthreads();
    if (i != k) {
      aug[i * 33 + j]      -= f * aug[k * 33 + j];
      aug[i * 33 + 16 + j] -= f * aug[k * 33 + 16 + j];
    }
    __syncthreads();
  }
  { int i = t >> 4, j = t & 15; Ml[t] = aug[i * 33 + 16 + j]; }
  __syncthreads();

  if (t < NP) {
    float r_ = rsdl[t];
#pragma unroll
    for (int j = 0; j < NQ; ++j) {
      float acc = 0.f;
#pragma unroll
      for (int q = 0; q < NQ; ++q) acc = fmaf(Ml[j * 16 + q], Hl[q * NP + t], acc);
      HMl[j * NP + t] = acc * r_;
    }
  }
  __syncthreads();

  { int j = t >> 4, l = t & 15;
    float p = 0.f;
    for (int pp = l; pp < NP; pp += 16) p = fmaf(mul[pp], HMl[j * NP + pp], p);
    red[t] = p; }
  __syncthreads();
  if (t < NQ) { float v = 0.f; for (int k = 0; k < 16; ++k) v += red[t * 16 + k]; el[t] = v; }
  __syncthreads();

  if (m < 3) {
    float* dst = hm + (size_t)s * HM_STRIDE;
    for (int i = t; i < NQ * NP; i += 256) dst[i] = HMl[i];
    if (t < NQ) dst[NQ * NP + t] = el[t];
  } else {
    if (t < 14) n7[t] = calc_w<7>(t, &w7[t * 8], l7[t]);
    __syncthreads();
    if (t < 98) {
      int oy = t / 7, iy = t - oy * 7;
      int k = iy - l7[oy];
      Radj[oy * 7 + iy] = (k >= 0 && k < n7[oy]) ? w7[oy * 8 + k] : 0.f;
    }
    __syncthreads();
    for (int i = t; i < NQ * 7 * 14; i += 256) {   // t2[j][iy][ox]
      int j = i / 98, rem = i - j * 98, iy = rem / 14, ox = rem - iy * 14;
      float acc = 0.f;
#pragma unroll
      for (int oy = 0; oy < 14; ++oy) acc = fmaf(Radj[oy * 7 + iy], HMl[j * NP + oy * 14 + ox], acc);
      t2[i] = acc;
    }
    __syncthreads();
    float* dst = hm + (size_t)s * HM3_STRIDE;
    for (int i = t; i < NQ * 49; i += 256) {       // dst[j][iy][ix]
      int j = i / 49, rem = i - j * 49, iy = rem / 7, ix = rem - iy * 7;
      float acc = 0.f;
#pragma unroll
      for (int ox = 0; ox < 14; ++ox) acc = fmaf(Radj[ox * 7 + ix], t2[j * 98 + iy * 14 + ox], acc);
      dst[i] = acc;
    }
    if (t < NQ) dst[NQ * 49 + t] = el[t];
  }
}

// ---------- K3: b[cc][j] = dot(row, HM[j]) - e[j]; out = var_j(b) ----------
#define CC3 32
struct VarArgs {
  const float* src[4];
  const float* hm[4];
  int cm[4];
  int ooff[4];
};

// grid: m0 [0,256) m1 [256,768) m2 [768,1792) m3 [1792,3840)
__global__ __launch_bounds__(512) void k_var(VarArgs A, float* __restrict__ out) {
  __shared__ __align__(16) float tile[CC3 * NP];
  __shared__ __align__(16) float hml[NQ * NP];
  __shared__ float el[NQ];
  int b = blockIdx.x;
  int m;
  if (b < 256)       { m = 0; }
  else if (b < 768)  { m = 1; b -= 256; }
  else if (b < 1792) { m = 2; b -= 768; }
  else               { m = 3; b -= 1792; }
  const int t = threadIdx.x;
  const int cc = t >> 4, j = t & 15;

  if (m < 3) {
    const int cm = A.cm[m];
    const int nch = cm / CC3;
    const int s = b / nch;
    const int ch = b % nch;
    const float4* src = (const float4*)(A.src[m] + ((size_t)s * cm + ch * CC3) * NP);
    float4* t4 = (float4*)tile;
    for (int i = t; i < CC3 * NP / 4; i += 512) t4[i] = src[i];
    const float4* hsrc = (const float4*)(A.hm[m] + (size_t)s * HM_STRIDE);
    float4* h4 = (float4*)hml;
    for (int i = t; i < NQ * NP / 4; i += 512) h4[i] = hsrc[i];
    if (t < NQ) el[t] = A.hm[m][(size_t)s * HM_STRIDE + NQ * NP + t];
    __syncthreads();

    const float4* tr = (const float4*)(tile + cc * NP);
    const float4* hr = (const float4*)(hml + j * NP);
    float acc = 0.f;
#pragma unroll 7
    for (int p4 = 0; p4 < NP / 4; ++p4) {
      float4 a = tr[p4], b2 = hr[p4];
      acc = fmaf(a.x, b2.x, acc);
      acc = fmaf(a.y, b2.y, acc);
      acc = fmaf(a.z, b2.z, acc);
      acc = fmaf(a.w, b2.w, acc);
    }
    float bv = acc - el[j];
    float s1 = bv;
    s1 += __shfl_xor(s1, 1, 16); s1 += __shfl_xor(s1, 2, 16);
    s1 += __shfl_xor(s1, 4, 16); s1 += __shfl_xor(s1, 8, 16);
    float mean = s1 * (1.0f / 16.0f);
    float d = bv - mean;
    float s2 = d * d;
    s2 += __shfl_xor(s2, 1, 16); s2 += __shfl_xor(s2, 2, 16);
    s2 += __shfl_xor(s2, 4, 16); s2 += __shfl_xor(s2, 8, 16);
    if (j == 0) out[(size_t)s * OUTW + A.ooff[m] + ch * CC3 + cc] = s2 * (1.0f / 15.0f);
  } else {
    const int s = b / 64;
    const int ch = b % 64;
    const float4* src = (const float4*)(A.src[3] + ((size_t)s * 2048 + ch * CC3) * 49);
    float4* t4 = (float4*)tile;
    for (int i = t; i < CC3 * 49 / 4; i += 512) t4[i] = src[i];
    const float4* hsrc = (const float4*)(A.hm[3] + (size_t)s * HM3_STRIDE);
    float4* h4 = (float4*)hml;
    for (int i = t; i < NQ * 49 / 4; i += 512) h4[i] = hsrc[i];
    if (t < NQ) el[t] = A.hm[3][(size_t)s * HM3_STRIDE + NQ * 49 + t];
    __syncthreads();

    const float* tr = tile + cc * 49;
    const float* hr = hml + j * 49;
    float acc = 0.f;
#pragma unroll
    for (int i = 0; i < 49; ++i) acc = fmaf(tr[i], hr[i], acc);
    float bv = acc - el[j];
    float s1 = bv;
    s1 += __shfl_xor(s1, 1, 16); s1 += __shfl_xor(s1, 2, 16);
    s1 += __shfl_xor(s1, 4, 16); s1 += __shfl_xor(s1, 8, 16);
    float mean = s1 * (1.0f / 16.0f);
    float d = bv - mean;
    float s2 = d * d;
    s2 += __shfl_xor(s2, 1, 16); s2 += __shfl_xor(s2, 2, 16);
    s2 += __shfl_xor(s2, 4, 16); s2 += __shfl_xor(s2, 8, 16);
    if (j == 0) out[(size_t)s * OUTW + 1792 + ch * CC3 + cc] = s2 * (1.0f / 15.0f);
  }
}

extern "C" void kernel_launch(void* const* d_in, const int* in_sizes, int n_in,
                              void* d_out, int out_size, void* d_ws, size_t ws_size,
                              hipStream_t stream) {
  const float* x0 = (const float*)d_in[0];
  const float* W0 = (const float*)d_in[1];
  const float* x1 = (const float*)d_in[2];
  const float* W1 = (const float*)d_in[3];
  const float* x2 = (const float*)d_in[4];
  const float* W2 = (const float*)d_in[5];
  const float* x3 = (const float*)d_in[6];
  const float* W3 = (const float*)d_in[7];
  float* out = (float*)d_out;
  float* ws = (float*)d_ws;

  // workspace layout (floats)
  float* xr0 = ws;                                   // 32*256*196
  float* xr1 = xr0 + (size_t)NB * 256 * NP;          // 32*512*196
  float* part0 = xr1 + (size_t)NB * 512 * NP;
  size_t plm = (size_t)NB * 32 * 18 * NP;            // per member
  float* part1 = part0 + plm;
  float* part2 = part1 + plm;
  float* part3 = part2 + plm;
  float* hm0 = part3 + plm;
  float* hm1 = hm0 + (size_t)NB * HM_STRIDE;
  float* hm2 = hm1 + (size_t)NB * HM_STRIDE;
  float* hm3 = hm2 + (size_t)NB * HM_STRIDE;         // 32*800

  // K1: single launch, all members (m0 blocks first — longest work first)
  RSArgs R;
  R.x[0] = x0; R.x[1] = x1; R.x[2] = x2; R.x[3] = x3;
  R.W[0] = W0; R.W[1] = W1; R.W[2] = W2; R.W[3] = W3;
  R.xr[0] = xr0; R.xr[1] = xr1;
  R.part[0] = part0; R.part[1] = part1; R.part[2] = part2; R.part[3] = part3;
  k_rs_all<<<6144, 256, 0, stream>>>(R);

  // K2: head
  HeadArgs A;
  A.part[0] = part0; A.part[1] = part1; A.part[2] = part2; A.part[3] = part3;
  A.W[0] = W0; A.W[1] = W1; A.W[2] = W2; A.W[3] = W3;
  A.hm[0] = hm0; A.hm[1] = hm1; A.hm[2] = hm2; A.hm[3] = hm3;
  A.cm[0] = 256; A.cm[1] = 512; A.cm[2] = 1024; A.cm[3] = 2048;
  k_head<<<dim3(NB, 4), 256, 0, stream>>>(A);

  // K3: var
  VarArgs V;
  V.src[0] = xr0; V.src[1] = xr1; V.src[2] = x2; V.src[3] = x3;
  V.hm[0] = hm0; V.hm[1] = hm1; V.hm[2] = hm2; V.hm[3] = hm3;
  V.cm[0] = 256; V.cm[1] = 512; V.cm[2] = 1024; V.cm[3] = 2048;
  V.ooff[0] = 0; V.ooff[1] = 256; V.ooff[2] = 768; V.ooff[3] = 1792;
  k_var<<<3840, 512, 0, stream>>>(V, out);
  (void)in_sizes; (void)n_in; (void)out_size; (void)ws_size;
}

// Round 16
// 162.252 us; speedup vs baseline: 3.0469x; 1.0257x over previous
//
#include <hip/hip_runtime.h>
#include <math.h>

#define NB 32
#define NQ 16
#define NP 196
#define OUTW 3840
#define HM_STRIDE (NQ * NP + NQ)   // 3152, members 0..2
#define HM3_STRIDE (NQ * 49 + NQ)  // 800, member 3

// ---------- resize weights (jax.image.resize, triangle kernel, antialias=True) ----------
template<int N>
__device__ __forceinline__ int calc_w(int i, float* w, int& lo) {
  constexpr float inv = (float)N / 14.0f;          // 4, 2, 0.5 — exact
  constexpr float ks  = (inv > 1.0f) ? inv : 1.0f; // kernel_scale = max(inv_scale, 1)
  constexpr float rks = 1.0f / ks;
  float sf = ((float)i + 0.5f) * inv - 0.5f;
  int l = (int)ceilf(sf - ks);
  int h = (int)floorf(sf + ks);
  if (l < 0) l = 0;
  if (h > N - 1) h = N - 1;
  int n = h - l + 1;
  float sum = 0.f;
  for (int k = 0; k < n; ++k) {
    float t = 1.0f - fabsf((float)(l + k) - sf) * rks;
    t = t > 0.f ? t : 0.f;
    w[k] = t; sum += t;
  }
  float r = 1.0f / sum;
  for (int k = 0; k < n; ++k) w[k] *= r;
  for (int k = n; k < 8; ++k) w[k] = 0.f;
  lo = l;
  return n;
}

// ---------- per-branch LDS overlays (manually unioned through one smem buffer) ----------
struct SM0 {                       // member 0: 15.9 KB
  float tmp[8 * 30 * 15];
  float wxs[14 * 8];
  float wya[14 * 8];
  int lya[14], nya[14];
  float wl[NQ * 8];
};
struct SM1 {                       // member 1: 16.2 KB
  float tmp[16 * 15 * 15];
  float wxs[14 * 4];
  float wya[14 * 8];
  int lya[14], nya[14];
  float wl[NQ * 16];
};
struct SM3 {                       // member 3: 17.3 KB
  float xl[64 * 49 + 16];
  float wl[NQ * 64];
  float w7a[14 * 8];
  int l7a[14], n7a[14];
};

// ---------- member 0 body (56->14), 3-load branch-free horizontal, pixel-split ----------
__device__ __forceinline__ void rs0_body(const float* __restrict__ x,
    const float* __restrict__ W, float* __restrict__ xr,
    float* __restrict__ part, int b, SM0& sh) {
  constexpr int N = 56, CH_BLK = 8, cm = 256, NR = 30;
  const int t = threadIdx.x;
  const int s = b >> 6, chunk = (b >> 1) & 31, half = b & 1;
  const int oy0 = half * 7;
  const int r0 = half ? 26 : 0;
  const int c0 = chunk * CH_BLK;

  if (t < 14) {
    float w[8]; int lo; int n = calc_w<N>(t, w, lo);
    int off = lo - (4 * t - 2);
    for (int k = 0; k < 8; ++k) sh.wxs[t * 8 + k] = 0.f;
    for (int k = 0; k < n; ++k) sh.wxs[t * 8 + off + k] = w[k];
  } else if (t >= 64 && t < 78) {
    int i = t - 64; sh.nya[i] = calc_w<N>(i, &sh.wya[i * 8], sh.lya[i]);
  }
  for (int i = t; i < NQ * CH_BLK; i += 256) {
    int q = i / CH_BLK, cc = i - q * CH_BLK;
    sh.wl[i] = W[q * cm + c0 + cc];
  }
  __syncthreads();

  // P1: 3 unconditional clamped overlapping loads per lane (no shfl, no exec
  // branch around loads) -> independent loads the scheduler can pipeline.
  // Position-aligned zero-padded wxs makes clamped boundary values *0.
  {
    const int wv = t >> 6, lane = t & 63;
    const int rr = lane / 14, j = lane - rr * 14;
    const bool act = lane < 56;
    const int e = 4 * j;
    const int ea = (e >= 4) ? e - 4 : 0;
    const int ec = (e <= 48) ? e + 4 : 52;
    const float* wx = &sh.wxs[j * 8];
#pragma unroll 2
    for (int g = wv; g < 60; g += 4) {
      int R = g * 4 + rr;
      R = (R < 239) ? R : 239;            // clamp: lanes 56-63 / tail stay in-bounds
      const int pl = R / NR, r = r0 + (R - pl * NR);
      const float* row = x + (((size_t)(s * cm + c0 + pl)) * N + r) * N;
      float4 a = *(const float4*)(row + ea);
      float4 bv = *(const float4*)(row + e);
      float4 c = *(const float4*)(row + ec);
      float acc = wx[0] * a.z + wx[1] * a.w + wx[2] * bv.x + wx[3] * bv.y
                + wx[4] * bv.z + wx[5] * bv.w + wx[6] * c.x + wx[7] * c.y;
      if (act) sh.tmp[R * 15 + j] = acc;
    }
  }
  __syncthreads();

  if (t < 98) {
    const int dy = t / 14, ox = t - dy * 14;
    const int oy = oy0 + dy;
    const int p = oy * 14 + ox;
    const int ny = sh.nya[oy], lyr = sh.lya[oy] - r0;
    const float* wy = &sh.wya[oy * 8];
    float s1 = 0.f, s2 = 0.f, y[NQ];
#pragma unroll
    for (int q = 0; q < NQ; ++q) y[q] = 0.f;
#pragma unroll 2
    for (int pl = 0; pl < CH_BLK; ++pl) {
      const float* tc = &sh.tmp[(pl * NR + lyr) * 15 + ox];
      float acc = 0.f;
      for (int k = 0; k < ny; ++k) acc = fmaf(wy[k], tc[k * 15], acc);
      xr[((size_t)s * cm + c0 + pl) * NP + p] = acc;
      s1 += acc; s2 = fmaf(acc, acc, s2);
#pragma unroll
      for (int q = 0; q < NQ; ++q) y[q] = fmaf(sh.wl[q * CH_BLK + pl], acc, y[q]);
    }
    float* pb = part + (size_t)(s * 32 + chunk) * 18 * NP + p;
    pb[0] = s1;
    pb[NP] = s2;
#pragma unroll
    for (int q = 0; q < NQ; ++q) pb[(size_t)(2 + q) * NP] = y[q];
  }
}

// ---------- member 1 body (28->14), 3-load branch-free horizontal, pixel-split ----------
__device__ __forceinline__ void rs1_body(const float* __restrict__ x,
    const float* __restrict__ W, float* __restrict__ xr,
    float* __restrict__ part, int b, SM1& sh) {
  constexpr int N = 28, CH_BLK = 16, cm = 512, NR = 15;
  const int t = threadIdx.x;
  const int s = b >> 6, chunk = (b >> 1) & 31, half = b & 1;
  const int oy0 = half * 7;
  const int r0 = half ? 13 : 0;
  const int c0 = chunk * CH_BLK;

  if (t < 14) {
    float w[8]; int lo; int n = calc_w<N>(t, w, lo);
    int off = lo - (2 * t - 1);
    for (int k = 0; k < 4; ++k) sh.wxs[t * 4 + k] = 0.f;
    for (int k = 0; k < n; ++k) sh.wxs[t * 4 + off + k] = w[k];
  } else if (t >= 64 && t < 78) {
    int i = t - 64; sh.nya[i] = calc_w<N>(i, &sh.wya[i * 8], sh.lya[i]);
  }
  for (int i = t; i < NQ * CH_BLK; i += 256) {
    int q = i / CH_BLK, cc = i - q * CH_BLK;
    sh.wl[i] = W[q * cm + c0 + cc];
  }
  __syncthreads();

  // P1: lane = rr*7 + j, 2 outputs/lane, 3 unconditional clamped loads
  {
    const int wv = t >> 6, lane = t & 63;
    const int rr = lane / 7, j = lane - rr * 7;
    const bool act = lane < 56;
    const int e = 4 * j;
    const int ea = (e >= 4) ? e - 4 : 0;
    const int ec = (e <= 20) ? e + 4 : 24;
    const int ox0 = 2 * j;
    const float* w0 = &sh.wxs[ox0 * 4];
    const float* w1 = &sh.wxs[(ox0 + 1) * 4];
#pragma unroll 2
    for (int g = wv; g < 30; g += 4) {
      int R = g * 8 + rr;
      R = (R < 239) ? R : 239;
      const int pl = R / NR, r = r0 + (R - pl * NR);
      const float* row = x + (((size_t)(s * cm + c0 + pl)) * N + r) * N;
      float4 a = *(const float4*)(row + ea);
      float4 bv = *(const float4*)(row + e);
      float4 c = *(const float4*)(row + ec);
      float acc0 = w0[0] * a.w + w0[1] * bv.x + w0[2] * bv.y + w0[3] * bv.z;
      float acc1 = w1[0] * bv.y + w1[1] * bv.z + w1[2] * bv.w + w1[3] * c.x;
      if (act) {
        sh.tmp[R * 15 + ox0] = acc0;
        sh.tmp[R * 15 + ox0 + 1] = acc1;
      }
    }
  }
  __syncthreads();

  if (t < 98) {
    const int dy = t / 14, ox = t - dy * 14;
    const int oy = oy0 + dy;
    const int p = oy * 14 + ox;
    const int ny = sh.nya[oy], lyr = sh.lya[oy] - r0;
    const float* wy = &sh.wya[oy * 8];
    float s1 = 0.f, s2 = 0.f, y[NQ];
#pragma unroll
    for (int q = 0; q < NQ; ++q) y[q] = 0.f;
#pragma unroll 2
    for (int pl = 0; pl < CH_BLK; ++pl) {
      const float* tc = &sh.tmp[(pl * NR + lyr) * 15 + ox];
      float acc = 0.f;
      for (int k = 0; k < ny; ++k) acc = fmaf(wy[k], tc[k * 15], acc);
      xr[((size_t)s * cm + c0 + pl) * NP + p] = acc;
      s1 += acc; s2 = fmaf(acc, acc, s2);
#pragma unroll
      for (int q = 0; q < NQ; ++q) y[q] = fmaf(sh.wl[q * CH_BLK + pl], acc, y[q]);
    }
    float* pb = part + (size_t)(s * 32 + chunk) * 18 * NP + p;
    pb[0] = s1;
    pb[NP] = s2;
#pragma unroll
    for (int q = 0; q < NQ; ++q) pb[(size_t)(2 + q) * NP] = y[q];
  }
}

// ---------- member 2 body (identity resize), register-direct (r12-exact) ----------
__device__ __forceinline__ void rs2_body(const float* __restrict__ x,
    const float* __restrict__ W, float* __restrict__ part, int b) {
  const int t = threadIdx.x;
  if (t >= NP) return;
  const int s = b >> 5, chunk = b & 31;
  const int c0 = chunk * 32;
  const float* src = x + ((size_t)s * 1024 + c0) * NP + t;
  float s1 = 0.f, s2 = 0.f, y[NQ];
#pragma unroll
  for (int q = 0; q < NQ; ++q) y[q] = 0.f;
  for (int c = 0; c < 32; ++c) {
    float v = src[(size_t)c * NP];
    s1 += v; s2 = fmaf(v, v, s2);
#pragma unroll
    for (int q = 0; q < NQ; ++q) y[q] = fmaf(W[q * 1024 + c0 + c], v, y[q]);
  }
  float* pb = part + (size_t)(s * 32 + chunk) * 18 * NP + t;
  pb[0] = s1;
  pb[NP] = s2;
#pragma unroll
  for (int q = 0; q < NQ; ++q) pb[(size_t)(2 + q) * NP] = y[q];
}

// ---------- member 3 body (7->14 upsample, <=2x2 taps, no xr) (r12-exact) ----------
__device__ __forceinline__ void rs3_body(const float* __restrict__ x,
    const float* __restrict__ W, float* __restrict__ part, int b, SM3& sh) {
  const int t = threadIdx.x;
  const int s = b >> 5, chunk = b & 31;
  const int c0 = chunk * 64;

  if (t < 14) sh.n7a[t] = calc_w<7>(t, &sh.w7a[t * 8], sh.l7a[t]);
  for (int i = t; i < NQ * 64; i += 256) {
    int q = i >> 6, cc = i & 63;
    sh.wl[i] = W[q * 2048 + c0 + cc];
  }
  const float4* src4 = (const float4*)(x + ((size_t)s * 2048 + c0) * 49);
  float4* x4 = (float4*)sh.xl;
  for (int i = t; i < 64 * 49 / 4; i += 256) x4[i] = src4[i];
  __syncthreads();

  if (t < NP) {
    const int oy = t / 14, ox = t - oy * 14;
    const int ly = sh.l7a[oy], lx = sh.l7a[ox];
    const float wy0 = sh.w7a[oy * 8], wy1 = (sh.n7a[oy] > 1) ? sh.w7a[oy * 8 + 1] : 0.f;
    const float wx0 = sh.w7a[ox * 8], wx1 = (sh.n7a[ox] > 1) ? sh.w7a[ox * 8 + 1] : 0.f;
    const int base0 = ly * 7 + lx;
    float s1 = 0.f, s2 = 0.f, y[NQ];
#pragma unroll
    for (int q = 0; q < NQ; ++q) y[q] = 0.f;
    for (int c = 0; c < 64; ++c) {
      const float* bb = &sh.xl[c * 49 + base0];
      float v = wy0 * fmaf(wx1, bb[1], wx0 * bb[0]) + wy1 * fmaf(wx1, bb[8], wx0 * bb[7]);
      s1 += v; s2 = fmaf(v, v, s2);
#pragma unroll
      for (int q = 0; q < NQ; ++q) y[q] = fmaf(sh.wl[q * 64 + c], v, y[q]);
    }
    float* pb = part + (size_t)(s * 32 + chunk) * 18 * NP + t;
    pb[0] = s1;
    pb[NP] = s2;
#pragma unroll
    for (int q = 0; q < NQ; ++q) pb[(size_t)(2 + q) * NP] = y[q];
  }
}

// ---------- K1: ALL members in one launch (6144 blocks, no grid drains) ----------
// grid: m0 [0,2048) m1 [2048,4096) m2 [4096,5120) m3 [5120,6144)
struct RSArgs {
  const float* x[4];
  const float* W[4];
  float* xr[2];
  float* part[4];
};

__global__ __launch_bounds__(256, 8) void k_rs_all(RSArgs A) {
  __shared__ __align__(16) char smem[17280];   // union of SM0/SM1/SM3 (max 17.3 KB)
  int b = blockIdx.x;
  if (b < 2048) {
    rs0_body(A.x[0], A.W[0], A.xr[0], A.part[0], b, *(SM0*)smem);
  } else if (b < 4096) {
    rs1_body(A.x[1], A.W[1], A.xr[1], A.part[1], b - 2048, *(SM1*)smem);
  } else if (b < 5120) {
    rs2_body(A.x[2], A.W[2], A.part[2], b - 4096);
  } else {
    rs3_body(A.x[3], A.W[3], A.part[3], b - 5120, *(SM3*)smem);
  }
}

// ---------- K2: combine partials, H, G^-1, HM = rsd*(H^T M), e; m3: adjoint HM ----------
struct HeadArgs {
  const float* part[4];
  const float* W[4];
  float* hm[4];
  int cm[4];
};

__global__ __launch_bounds__(256) void k_head(HeadArgs A) {
  const int m = blockIdx.y, s = blockIdx.x, t = threadIdx.x;
  const int cm = A.cm[m];
  const float* W = A.W[m];
  const float* part = A.part[m];
  float* hm = A.hm[m];

  __shared__ float red[256];
  __shared__ float wsum[NQ];
  __shared__ float Hl[NQ * NP];
  __shared__ float HMl[NQ * NP];
  __shared__ float mul[NP], rsdl[NP];
  __shared__ float aug[16 * 33];
  __shared__ float Ml[256];
  __shared__ float el[NQ];
  __shared__ float w7[14 * 8];
  __shared__ int l7[14], n7[14];
  __shared__ float Radj[14 * 7];
  __shared__ float t2[NQ * 7 * 14];

  { int q = t >> 4, l = t & 15;
    float p = 0.f;
    for (int c = l; c < cm; c += 16) p += W[q * cm + c];
    red[t] = p; }
  __syncthreads();
  if (t < NQ) { float v = 0.f; for (int k = 0; k < 16; ++k) v += red[t * 16 + k]; wsum[t] = v; }
  __syncthreads();

  if (t < NP) {
    float s1 = 0.f, s2 = 0.f, y[NQ];
#pragma unroll
    for (int q = 0; q < NQ; ++q) y[q] = 0.f;
    for (int ch = 0; ch < 32; ++ch) {
      const float* pb = part + (size_t)(s * 32 + ch) * 18 * NP + t;
      s1 += pb[0];
      s2 += pb[NP];
#pragma unroll
      for (int q = 0; q < NQ; ++q) y[q] += pb[(size_t)(2 + q) * NP];
    }
    float mu = s1 / (float)cm;
    float var = (s2 - s1 * mu) / (float)(cm - 1);
    float rsd = (var > 0.f) ? (1.0f / sqrtf(var)) : 0.f;
    mul[t] = mu; rsdl[t] = rsd;
#pragma unroll
    for (int q = 0; q < NQ; ++q) {
      float arg = (y[q] - wsum[q] * mu) * rsd;
      Hl[q * NP + t] = 1.0f / (1.0f + expf(-arg));
    }
  }
  __syncthreads();

  { int q1 = t >> 4, q2 = t & 15;
    float g = 0.f;
    for (int p = 0; p < NP; ++p) g = fmaf(Hl[q1 * NP + p], Hl[q2 * NP + p], g);
    aug[q1 * 33 + q2] = g;
    aug[q1 * 33 + 16 + q2] = (q1 == q2) ? 1.0f : 0.f; }
  __syncthreads();

  for (int k = 0; k < 16; ++k) {
    float rpv = 1.0f / aug[k * 33 + k];
    __syncthreads();
    if (t < 32) aug[k * 33 + t] *= rpv;
    __syncthreads();
    int i = t >> 4, j = t & 15;
    float f = aug[i * 33 + k];
    __syncthreads();
    if (i != k) {
      aug[i * 33 + j]      -= f * aug[k * 33 + j];
      aug[i * 33 + 16 + j] -= f * aug[k * 33 + 16 + j];
    }
    __syncthreads();
  }
  { int i = t >> 4, j = t & 15; Ml[t] = aug[i * 33 + 16 + j]; }
  __syncthreads();

  if (t < NP) {
    float r_ = rsdl[t];
#pragma unroll
    for (int j = 0; j < NQ; ++j) {
      float acc = 0.f;
#pragma unroll
      for (int q = 0; q < NQ; ++q) acc = fmaf(Ml[j * 16 + q], Hl[q * NP + t], acc);
      HMl[j * NP + t] = acc * r_;
    }
  }
  __syncthreads();

  { int j = t >> 4, l = t & 15;
    float p = 0.f;
    for (int pp = l; pp < NP; pp += 16) p = fmaf(mul[pp], HMl[j * NP + pp], p);
    red[t] = p; }
  __syncthreads();
  if (t < NQ) { float v = 0.f; for (int k = 0; k < 16; ++k) v += red[t * 16 + k]; el[t] = v; }
  __syncthreads();

  if (m < 3) {
    float* dst = hm + (size_t)s * HM_STRIDE;
    for (int i = t; i < NQ * NP; i += 256) dst[i] = HMl[i];
    if (t < NQ) dst[NQ * NP + t] = el[t];
  } else {
    if (t < 14) n7[t] = calc_w<7>(t, &w7[t * 8], l7[t]);
    __syncthreads();
    if (t < 98) {
      int oy = t / 7, iy = t - oy * 7;
      int k = iy - l7[oy];
      Radj[oy * 7 + iy] = (k >= 0 && k < n7[oy]) ? w7[oy * 8 + k] : 0.f;
    }
    __syncthreads();
    for (int i = t; i < NQ * 7 * 14; i += 256) {   // t2[j][iy][ox]
      int j = i / 98, rem = i - j * 98, iy = rem / 14, ox = rem - iy * 14;
      float acc = 0.f;
#pragma unroll
      for (int oy = 0; oy < 14; ++oy) acc = fmaf(Radj[oy * 7 + iy], HMl[j * NP + oy * 14 + ox], acc);
      t2[i] = acc;
    }
    __syncthreads();
    float* dst = hm + (size_t)s * HM3_STRIDE;
    for (int i = t; i < NQ * 49; i += 256) {       // dst[j][iy][ix]
      int j = i / 49, rem = i - j * 49, iy = rem / 7, ix = rem - iy * 7;
      float acc = 0.f;
#pragma unroll
      for (int ox = 0; ox < 14; ++ox) acc = fmaf(Radj[ox * 7 + ix], t2[j * 98 + iy * 14 + ox], acc);
      dst[i] = acc;
    }
    if (t < NQ) dst[NQ * 49 + t] = el[t];
  }
}

// ---------- K3: b[cc][j] = dot(row, HM[j]) - e[j]; out = var_j(b) ----------
#define CC3 32
struct VarArgs {
  const float* src[4];
  const float* hm[4];
  int cm[4];
  int ooff[4];
};

// grid: m0 [0,256) m1 [256,768) m2 [768,1792) m3 [1792,3840)
__global__ __launch_bounds__(512) void k_var(VarArgs A, float* __restrict__ out) {
  __shared__ __align__(16) float tile[CC3 * NP];
  __shared__ __align__(16) float hml[NQ * NP];
  __shared__ float el[NQ];
  int b = blockIdx.x;
  int m;
  if (b < 256)       { m = 0; }
  else if (b < 768)  { m = 1; b -= 256; }
  else if (b < 1792) { m = 2; b -= 768; }
  else               { m = 3; b -= 1792; }
  const int t = threadIdx.x;
  const int cc = t >> 4, j = t & 15;

  if (m < 3) {
    const int cm = A.cm[m];
    const int nch = cm / CC3;
    const int s = b / nch;
    const int ch = b % nch;
    const float4* src = (const float4*)(A.src[m] + ((size_t)s * cm + ch * CC3) * NP);
    float4* t4 = (float4*)tile;
    for (int i = t; i < CC3 * NP / 4; i += 512) t4[i] = src[i];
    const float4* hsrc = (const float4*)(A.hm[m] + (size_t)s * HM_STRIDE);
    float4* h4 = (float4*)hml;
    for (int i = t; i < NQ * NP / 4; i += 512) h4[i] = hsrc[i];
    if (t < NQ) el[t] = A.hm[m][(size_t)s * HM_STRIDE + NQ * NP + t];
    __syncthreads();

    const float4* tr = (const float4*)(tile + cc * NP);
    const float4* hr = (const float4*)(hml + j * NP);
    float acc = 0.f;
#pragma unroll 7
    for (int p4 = 0; p4 < NP / 4; ++p4) {
      float4 a = tr[p4], b2 = hr[p4];
      acc = fmaf(a.x, b2.x, acc);
      acc = fmaf(a.y, b2.y, acc);
      acc = fmaf(a.z, b2.z, acc);
      acc = fmaf(a.w, b2.w, acc);
    }
    float bv = acc - el[j];
    float s1 = bv;
    s1 += __shfl_xor(s1, 1, 16); s1 += __shfl_xor(s1, 2, 16);
    s1 += __shfl_xor(s1, 4, 16); s1 += __shfl_xor(s1, 8, 16);
    float mean = s1 * (1.0f / 16.0f);
    float d = bv - mean;
    float s2 = d * d;
    s2 += __shfl_xor(s2, 1, 16); s2 += __shfl_xor(s2, 2, 16);
    s2 += __shfl_xor(s2, 4, 16); s2 += __shfl_xor(s2, 8, 16);
    if (j == 0) out[(size_t)s * OUTW + A.ooff[m] + ch * CC3 + cc] = s2 * (1.0f / 15.0f);
  } else {
    const int s = b / 64;
    const int ch = b % 64;
    const float4* src = (const float4*)(A.src[3] + ((size_t)s * 2048 + ch * CC3) * 49);
    float4* t4 = (float4*)tile;
    for (int i = t; i < CC3 * 49 / 4; i += 512) t4[i] = src[i];
    const float4* hsrc = (const float4*)(A.hm[3] + (size_t)s * HM3_STRIDE);
    float4* h4 = (float4*)hml;
    for (int i = t; i < NQ * 49 / 4; i += 512) h4[i] = hsrc[i];
    if (t < NQ) el[t] = A.hm[3][(size_t)s * HM3_STRIDE + NQ * 49 + t];
    __syncthreads();

    const float* tr = tile + cc * 49;
    const float* hr = hml + j * 49;
    float acc = 0.f;
#pragma unroll
    for (int i = 0; i < 49; ++i) acc = fmaf(tr[i], hr[i], acc);
    float bv = acc - el[j];
    float s1 = bv;
    s1 += __shfl_xor(s1, 1, 16); s1 += __shfl_xor(s1, 2, 16);
    s1 += __shfl_xor(s1, 4, 16); s1 += __shfl_xor(s1, 8, 16);
    float mean = s1 * (1.0f / 16.0f);
    float d = bv - mean;
    float s2 = d * d;
    s2 += __shfl_xor(s2, 1, 16); s2 += __shfl_xor(s2, 2, 16);
    s2 += __shfl_xor(s2, 4, 16); s2 += __shfl_xor(s2, 8, 16);
    if (j == 0) out[(size_t)s * OUTW + 1792 + ch * CC3 + cc] = s2 * (1.0f / 15.0f);
  }
}

extern "C" void kernel_launch(void* const* d_in, const int* in_sizes, int n_in,
                              void* d_out, int out_size, void* d_ws, size_t ws_size,
                              hipStream_t stream) {
  const float* x0 = (const float*)d_in[0];
  const float* W0 = (const float*)d_in[1];
  const float* x1 = (const float*)d_in[2];
  const float* W1 = (const float*)d_in[3];
  const float* x2 = (const float*)d_in[4];
  const float* W2 = (const float*)d_in[5];
  const float* x3 = (const float*)d_in[6];
  const float* W3 = (const float*)d_in[7];
  float* out = (float*)d_out;
  float* ws = (float*)d_ws;

  // workspace layout (floats)
  float* xr0 = ws;                                   // 32*256*196
  float* xr1 = xr0 + (size_t)NB * 256 * NP;          // 32*512*196
  float* part0 = xr1 + (size_t)NB * 512 * NP;
  size_t plm = (size_t)NB * 32 * 18 * NP;            // per member
  float* part1 = part0 + plm;
  float* part2 = part1 + plm;
  float* part3 = part2 + plm;
  float* hm0 = part3 + plm;
  float* hm1 = hm0 + (size_t)NB * HM_STRIDE;
  float* hm2 = hm1 + (size_t)NB * HM_STRIDE;
  float* hm3 = hm2 + (size_t)NB * HM_STRIDE;         // 32*800

  // K1: single launch, all members (m0 blocks first — longest work first)
  RSArgs R;
  R.x[0] = x0; R.x[1] = x1; R.x[2] = x2; R.x[3] = x3;
  R.W[0] = W0; R.W[1] = W1; R.W[2] = W2; R.W[3] = W3;
  R.xr[0] = xr0; R.xr[1] = xr1;
  R.part[0] = part0; R.part[1] = part1; R.part[2] = part2; R.part[3] = part3;
  k_rs_all<<<6144, 256, 0, stream>>>(R);

  // K2: head
  HeadArgs A;
  A.part[0] = part0; A.part[1] = part1; A.part[2] = part2; A.part[3] = part3;
  A.W[0] = W0; A.W[1] = W1; A.W[2] = W2; A.W[3] = W3;
  A.hm[0] = hm0; A.hm[1] = hm1; A.hm[2] = hm2; A.hm[3] = hm3;
  A.cm[0] = 256; A.cm[1] = 512; A.cm[2] = 1024; A.cm[3] = 2048;
  k_head<<<dim3(NB, 4), 256, 0, stream>>>(A);

  // K3: var
  VarArgs V;
  V.src[0] = xr0; V.src[1] = xr1; V.src[2] = x2; V.src[3] = x3;
  V.hm[0] = hm0; V.hm[1] = hm1; V.hm[2] = hm2; V.hm[3] = hm3;
  V.cm[0] = 256; V.cm[1] = 512; V.cm[2] = 1024; V.cm[3] = 2048;
  V.ooff[0] = 0; V.ooff[1] = 256; V.ooff[2] = 768; V.ooff[3] = 1792;
  k_var<<<3840, 512, 0, stream>>>(V, out);
  (void)in_sizes; (void)n_in; (void)out_size; (void)ws_size;
}